// Round 1
// baseline (603.112 us; speedup 1.0000x reference)
//
#include <hip/hip_runtime.h>
#include <math.h>

// ---------------- problem constants ----------------
#define TASKS 64
#define NB    4096
#define TDI   512     // token dim (K of GEMM1)
#define HDI   256     // hidden dim
#define VDI   484     // visual dim
#define VDP   512     // padded visual dim
#define BM    64      // rows per workgroup
#define BK    32      // K chunk per stage step (one MFMA K)

// ---------------- ws layout (bytes) ----------------
// All bf16 arrays pre-tiled into the exact [tile][kg][n][8] chunk order the
// main kernel's global_load_lds consumes (streaming, coalesced).
#define WS_TF   ((size_t)0)                       // [64rb][16ks][4kg][64m][8]  = 2,097,152 ush
#define WS_W1H  (WS_TF  + (size_t)2097152 * 2)    // [64t][16ks][4kg][256n][8]  = 8,388,608 ush
#define WS_W1L  (WS_W1H + (size_t)8388608 * 2)
#define WS_W2H  (WS_W1L + (size_t)8388608 * 2)    // [64t][4pass][8ks][4kg][128n][8] = 8,388,608 ush
#define WS_W2L  (WS_W2H + (size_t)8388608 * 2)
#define WS_CN   (WS_W2L + (size_t)8388608 * 2)    // 64 f32 (centroid norms)
#define WS_ACC  (WS_CN + 256)                     // 64 f32 (distance accumulators)
#define WS_END  (WS_ACC + 256)                    // ~68 MiB total

// ---------------- LDS layout (bytes), static 62976 ----------------
// Region R1 [0,20480):  phase1 {A@0 4KB, Bh@4096 16KB} ; phase3 {W2h@0 8KB, W2l@8192 8KB}
// Region R2 [20480,53248): phase1 {Bl@20480 16KB} ; phase2/3 {H' 32KB, layout [32kg][64m][8] bf16}
#define LDS_A    0
#define LDS_BH   4096
#define LDS_W2H  0
#define LDS_W2L  8192
#define LDS_BL   20480
#define LDS_HP   20480
#define LDS_B1   53248
#define LDS_G    54272
#define LDS_BE   55296
#define LDS_B2   56320   // 512 f32 (padded w/ 0)
#define LDS_CE   58368   // 512 f32 (padded w/ 0)
#define LDS_R0   60416   // [4w][64m] f32
#define LDS_R1   61440   // [4w][64m] f32
#define LDS_MU   62464   // 64 f32
#define LDS_RS   62720   // 64 f32
#define SMEM_BYTES 62976

typedef __bf16 bf16x8 __attribute__((ext_vector_type(8)));
typedef float  f32x4  __attribute__((ext_vector_type(4)));

__device__ __forceinline__ unsigned short f2bf(float x) {   // RNE float->bf16
  unsigned u = __float_as_uint(x);
  u += 0x7fffu + ((u >> 16) & 1u);
  return (unsigned short)(u >> 16);
}
__device__ __forceinline__ float bf2f(unsigned short h) {
  return __uint_as_float(((unsigned)h) << 16);
}

#define MFMA16(a, b, c) __builtin_amdgcn_mfma_f32_16x16x32_bf16((a), (b), (c), 0, 0, 0)

// Direct global->LDS 16B/lane async copy. LDS dest is wave-uniform base + lane*16;
// chunk = it*256 + tid  =>  (chunk & ~63) is wave-uniform.
__device__ __forceinline__ void load16(const void* g, const char* ldsRegion, int chunk) {
  __builtin_amdgcn_global_load_lds(
      (__attribute__((address_space(1))) void*)g,
      (__attribute__((address_space(3))) void*)(ldsRegion + (size_t)(chunk & ~63) * 16),
      16, 0, 0);
}

// ================= prepass: fp32 -> tiled bf16 (hi/lo split for weights) =================
extern "C" __global__ void prep_tf_k(const float* __restrict__ x, unsigned short* __restrict__ o) {
  int gid = blockIdx.x * 256 + threadIdx.x;          // [0, 524288)
  int b = gid >> 7;
  int k = (gid & 127) * 4;
  float4 v = *(const float4*)(x + (size_t)b * TDI + k);
  int rb = b >> 6, m = b & 63;
  int ks = k >> 5, kg = (k >> 3) & 3, j = k & 7;
  size_t off = (((size_t)(rb * 16 + ks) * 4 + kg) * 64 + m) * 8 + j;
  ushort4 u; u.x = f2bf(v.x); u.y = f2bf(v.y); u.z = f2bf(v.z); u.w = f2bf(v.w);
  *(ushort4*)(o + off) = u;
}

extern "C" __global__ void prep_w1_k(const float* __restrict__ x,
                                     unsigned short* __restrict__ oh,
                                     unsigned short* __restrict__ ol) {
  int gid = blockIdx.x * 256 + threadIdx.x;          // [0, 2097152)
  int t = gid >> 15;
  int rem = gid & 32767;
  int h = rem >> 7;
  int d = (rem & 127) * 4;
  float4 v = *(const float4*)(x + ((size_t)t * HDI + h) * TDI + d);
  int ks = d >> 5, kg = (d >> 3) & 3, j = d & 7;
  size_t off = (((size_t)(t * 16 + ks) * 4 + kg) * 256 + h) * 8 + j;
  ushort4 uh, ul;
  uh.x = f2bf(v.x); ul.x = f2bf(v.x - bf2f(uh.x));
  uh.y = f2bf(v.y); ul.y = f2bf(v.y - bf2f(uh.y));
  uh.z = f2bf(v.z); ul.z = f2bf(v.z - bf2f(uh.z));
  uh.w = f2bf(v.w); ul.w = f2bf(v.w - bf2f(uh.w));
  *(ushort4*)(oh + off) = uh;
  *(ushort4*)(ol + off) = ul;
}

extern "C" __global__ void prep_w2_k(const float* __restrict__ x,
                                     unsigned short* __restrict__ oh,
                                     unsigned short* __restrict__ ol) {
  int gid = blockIdx.x * 256 + threadIdx.x;          // [0, 2097152) over padded out space
  int t = gid >> 15;
  int rem = gid & 32767;
  int v = rem >> 6;
  int h = (rem & 63) * 4;
  float4 val;
  if (v < VDI) val = *(const float4*)(x + ((size_t)t * VDI + v) * HDI + h);
  else { val.x = 0.f; val.y = 0.f; val.z = 0.f; val.w = 0.f; }   // zero pad rows 484..511
  int pass = v >> 7, n = v & 127;
  int ks = h >> 5, kg = (h >> 3) & 3, j = h & 7;
  size_t off = ((((size_t)(t * 4 + pass) * 8 + ks) * 4 + kg) * 128 + n) * 8 + j;
  ushort4 uh, ul;
  uh.x = f2bf(val.x); ul.x = f2bf(val.x - bf2f(uh.x));
  uh.y = f2bf(val.y); ul.y = f2bf(val.y - bf2f(uh.y));
  uh.z = f2bf(val.z); ul.z = f2bf(val.z - bf2f(uh.z));
  uh.w = f2bf(val.w); ul.w = f2bf(val.w - bf2f(uh.w));
  *(ushort4*)(oh + off) = uh;
  *(ushort4*)(ol + off) = ul;
}

extern "C" __global__ void prep_cn_k(const float* __restrict__ cent,
                                     float* __restrict__ cnorm,
                                     float* __restrict__ accum) {
  int t = blockIdx.x, lane = threadIdx.x;            // <<<64, 64>>>
  float s = 0.f;
  for (int v = lane; v < VDI; v += 64) { float c = cent[(size_t)t * VDI + v]; s += c * c; }
  #pragma unroll
  for (int off = 32; off; off >>= 1) s += __shfl_xor(s, off);
  if (lane == 0) { cnorm[t] = sqrtf(s); accum[t] = 0.f; }
}

// ================= fused main kernel =================
extern "C" __global__ void __launch_bounds__(256, 2)
router_main(const unsigned short* __restrict__ tf,
            const unsigned short* __restrict__ w1h,
            const unsigned short* __restrict__ w1l,
            const unsigned short* __restrict__ w2h,
            const unsigned short* __restrict__ w2l,
            const float* __restrict__ b1,
            const float* __restrict__ gamma,
            const float* __restrict__ beta,
            const float* __restrict__ b2,
            const float* __restrict__ cent,
            const float* __restrict__ cnorm,
            float* __restrict__ accum) {
  __shared__ __align__(16) char smem[SMEM_BYTES];

  const int tid = threadIdx.x;
  const int bx  = blockIdx.x;
  // XCD swizzle (XCD ~ bx&7): each XCD works one task at a time -> task weights stay in its L2.
  const int t  = ((bx & 7) << 3) | (bx >> 9);
  const int rb = (bx >> 3) & 63;

  const int lane = tid & 63;
  const int w    = tid >> 6;       // wave id 0..3
  const int quad = lane >> 4;      // k-group / row-group selector
  const int l15  = lane & 15;

  // ---- preload per-task vectors into LDS ----
  {
    float* b1s = (float*)(smem + LDS_B1);
    float* gs  = (float*)(smem + LDS_G);
    float* bes = (float*)(smem + LDS_BE);
    float* b2s = (float*)(smem + LDS_B2);
    float* ces = (float*)(smem + LDS_CE);
    b1s[tid] = b1[(size_t)t * HDI + tid];
    gs[tid]  = gamma[(size_t)t * HDI + tid];
    bes[tid] = beta[(size_t)t * HDI + tid];
    int i0 = tid;
    b2s[i0] = (i0 < VDI) ? b2[(size_t)t * VDI + i0] : 0.f;
    ces[i0] = (i0 < VDI) ? cent[(size_t)t * VDI + i0] : 0.f;
    int i1 = tid + 256;
    b2s[i1] = (i1 < VDI) ? b2[(size_t)t * VDI + i1] : 0.f;
    ces[i1] = (i1 < VDI) ? cent[(size_t)t * VDI + i1] : 0.f;
  }

  f32x4 zero4 = {0.f, 0.f, 0.f, 0.f};
  f32x4 acc[4][4];
  #pragma unroll
  for (int rt = 0; rt < 4; ++rt)
    #pragma unroll
    for (int ct = 0; ct < 4; ++ct) acc[rt][ct] = zero4;

  // ================= Phase 1: GEMM1  H[64x256] = tfeat * W1^T (2-term hi/lo) =================
  #pragma unroll 1
  for (int ks = 0; ks < TDI / BK; ++ks) {
    // A tile: 256 chunks [4kg][64m][8]
    {
      size_t tileA = ((size_t)(rb * 16 + ks)) * 256;
      load16(tf + (tileA + tid) * 8, smem + LDS_A, tid);
    }
    // B tiles: 1024 chunks each [4kg][256n][8]
    size_t tile1 = ((size_t)(t * 16 + ks)) * 1024;
    #pragma unroll
    for (int it = 0; it < 4; ++it) {
      int c = it * 256 + tid;
      load16(w1h + (tile1 + c) * 8, smem + LDS_BH, c);
      load16(w1l + (tile1 + c) * 8, smem + LDS_BL, c);
    }
    __syncthreads();

    bf16x8 a[4];
    #pragma unroll
    for (int rt = 0; rt < 4; ++rt)
      a[rt] = *(const bf16x8*)(smem + LDS_A + (quad * 64 + rt * 16 + l15) * 16);
    #pragma unroll
    for (int ct = 0; ct < 4; ++ct) {
      int n = w * 64 + ct * 16 + l15;
      bf16x8 bh = *(const bf16x8*)(smem + LDS_BH + (quad * 256 + n) * 16);
      bf16x8 bl = *(const bf16x8*)(smem + LDS_BL + (quad * 256 + n) * 16);
      #pragma unroll
      for (int rt = 0; rt < 4; ++rt) {
        acc[rt][ct] = MFMA16(a[rt], bh, acc[rt][ct]);
        acc[rt][ct] = MFMA16(a[rt], bl, acc[rt][ct]);
      }
    }
    __syncthreads();
  }

  // ================= Phase 2: +b1, LayerNorm, GELU -> H' (bf16) in LDS =================
  {
    const float* b1s = (const float*)(smem + LDS_B1);
    float* red0 = (float*)(smem + LDS_R0);
    float* red1 = (float*)(smem + LDS_R1);
    // per-lane partial row sums over this wave's 64 columns
    #pragma unroll
    for (int rt = 0; rt < 4; ++rt)
      #pragma unroll
      for (int r = 0; r < 4; ++r) {
        float sv = 0.f, qv = 0.f;
        #pragma unroll
        for (int ct = 0; ct < 4; ++ct) {
          int col = w * 64 + ct * 16 + l15;
          float v = acc[rt][ct][r] + b1s[col];
          acc[rt][ct][r] = v;
          sv += v; qv += v * v;
        }
        sv += __shfl_xor(sv, 1); qv += __shfl_xor(qv, 1);
        sv += __shfl_xor(sv, 2); qv += __shfl_xor(qv, 2);
        sv += __shfl_xor(sv, 4); qv += __shfl_xor(qv, 4);
        sv += __shfl_xor(sv, 8); qv += __shfl_xor(qv, 8);
        if (l15 == 0) {
          int m = rt * 16 + quad * 4 + r;
          red0[w * 64 + m] = sv;
          red1[w * 64 + m] = qv;
        }
      }
    __syncthreads();
    if (tid < 64) {
      float s = red0[tid] + red0[64 + tid] + red0[128 + tid] + red0[192 + tid];
      float q = red1[tid] + red1[64 + tid] + red1[128 + tid] + red1[192 + tid];
      float mu = s * (1.f / HDI);
      float var = q * (1.f / HDI) - mu * mu;
      ((float*)(smem + LDS_MU))[tid] = mu;
      ((float*)(smem + LDS_RS))[tid] = rsqrtf(var + 1e-5f);
    }
    __syncthreads();
    const float* mus = (const float*)(smem + LDS_MU);
    const float* rss = (const float*)(smem + LDS_RS);
    const float* gs  = (const float*)(smem + LDS_G);
    const float* bes = (const float*)(smem + LDS_BE);
    #pragma unroll
    for (int rt = 0; rt < 4; ++rt)
      #pragma unroll
      for (int ct = 0; ct < 4; ++ct)
        #pragma unroll
        for (int r = 0; r < 4; ++r) {
          int col = w * 64 + ct * 16 + l15;
          int m   = rt * 16 + quad * 4 + r;
          float x = (acc[rt][ct][r] - mus[m]) * rss[m];
          x = x * gs[col] + bes[col];
          float g = 0.5f * x * (1.f + erff(x * 0.70710678118654752f));
          // H' layout [kg=col>>3][m][col&7]
          *(unsigned short*)(smem + LDS_HP + (size_t)((col >> 3) * 64 + m) * 16 + (col & 7) * 2) = f2bf(g);
        }
    __syncthreads();
  }

  // ================= Phase 3: GEMM2 (N in 4 passes of 128) + cosine epilogue =================
  float dotp[16], ssp[16];
  #pragma unroll
  for (int i = 0; i < 16; ++i) { dotp[i] = 0.f; ssp[i] = 0.f; }
  const float* b2s = (const float*)(smem + LDS_B2);
  const float* ces = (const float*)(smem + LDS_CE);

  #pragma unroll 1
  for (int pass = 0; pass < 4; ++pass) {
    f32x4 acc2[4][2];
    #pragma unroll
    for (int rt = 0; rt < 4; ++rt) { acc2[rt][0] = zero4; acc2[rt][1] = zero4; }

    #pragma unroll 1
    for (int ks = 0; ks < HDI / BK; ++ks) {
      size_t tile2 = ((size_t)((t * 4 + pass) * 8 + ks)) * 512;  // 512 chunks [4kg][128n][8]
      #pragma unroll
      for (int it = 0; it < 2; ++it) {
        int c = it * 256 + tid;
        load16(w2h + (tile2 + c) * 8, smem + LDS_W2H, c);
        load16(w2l + (tile2 + c) * 8, smem + LDS_W2L, c);
      }
      __syncthreads();

      bf16x8 a[4];
      #pragma unroll
      for (int rt = 0; rt < 4; ++rt)
        a[rt] = *(const bf16x8*)(smem + LDS_HP + ((ks * 4 + quad) * 64 + rt * 16 + l15) * 16);
      #pragma unroll
      for (int ct = 0; ct < 2; ++ct) {
        int n = w * 32 + ct * 16 + l15;
        bf16x8 bh = *(const bf16x8*)(smem + LDS_W2H + (quad * 128 + n) * 16);
        bf16x8 bl = *(const bf16x8*)(smem + LDS_W2L + (quad * 128 + n) * 16);
        #pragma unroll
        for (int rt = 0; rt < 4; ++rt) {
          acc2[rt][ct] = MFMA16(a[rt], bh, acc2[rt][ct]);
          acc2[rt][ct] = MFMA16(a[rt], bl, acc2[rt][ct]);
        }
      }
      __syncthreads();
    }

    // epilogue: accumulate v.c and |v|^2 per row (V never materialized)
    #pragma unroll
    for (int rt = 0; rt < 4; ++rt)
      #pragma unroll
      for (int ct = 0; ct < 2; ++ct)
        #pragma unroll
        for (int r = 0; r < 4; ++r) {
          int vcol = pass * 128 + w * 32 + ct * 16 + l15;
          if (vcol < VDI) {
            float val = acc2[rt][ct][r] + b2s[vcol];
            int i = rt * 4 + r;
            dotp[i] += val * ces[vcol];
            ssp[i]  += val * val;
          }
        }
  }

  // reduce per-row dot/ss across 16 col-lanes, then across waves via LDS
  #pragma unroll
  for (int i = 0; i < 16; ++i) {
    dotp[i] += __shfl_xor(dotp[i], 1); ssp[i] += __shfl_xor(ssp[i], 1);
    dotp[i] += __shfl_xor(dotp[i], 2); ssp[i] += __shfl_xor(ssp[i], 2);
    dotp[i] += __shfl_xor(dotp[i], 4); ssp[i] += __shfl_xor(ssp[i], 4);
    dotp[i] += __shfl_xor(dotp[i], 8); ssp[i] += __shfl_xor(ssp[i], 8);
  }
  {
    float* red0 = (float*)(smem + LDS_R0);
    float* red1 = (float*)(smem + LDS_R1);
    if (l15 == 0) {
      #pragma unroll
      for (int rt = 0; rt < 4; ++rt)
        #pragma unroll
        for (int r = 0; r < 4; ++r) {
          int m = rt * 16 + quad * 4 + r;
          red0[w * 64 + m] = dotp[rt * 4 + r];
          red1[w * 64 + m] = ssp[rt * 4 + r];
        }
    }
    __syncthreads();
    if (tid < 64) {
      float dot = red0[tid] + red0[64 + tid] + red0[128 + tid] + red0[192 + tid];
      float ss  = red1[tid] + red1[64 + tid] + red1[128 + tid] + red1[192 + tid];
      float cn  = fmaxf(cnorm[t], 1e-8f);
      float vn  = fmaxf(sqrtf(ss), 1e-8f);
      float part = 1.0f - dot / (vn * cn);
      part += __shfl_down(part, 32);
      part += __shfl_down(part, 16);
      part += __shfl_down(part, 8);
      part += __shfl_down(part, 4);
      part += __shfl_down(part, 2);
      part += __shfl_down(part, 1);
      if (tid == 0) atomicAdd(accum + t, part);
    }
  }
}

// ================= finalize: mean, argmin =================
extern "C" __global__ void finalize_k(const float* __restrict__ accum, float* __restrict__ out) {
  int t = threadIdx.x;                               // <<<1, 64>>>
  float d = accum[t] * (1.0f / (float)NB);
  out[t] = d;
  float bd = d; int bi = t;
  #pragma unroll
  for (int off = 32; off; off >>= 1) {
    float od = __shfl_xor(bd, off);
    int   oi = __shfl_xor(bi, off);
    if (od < bd || (od == bd && oi < bi)) { bd = od; bi = oi; }   // first-min tie-break
  }
  if (t == 0) out[64] = (float)bi;
}

extern "C" void kernel_launch(void* const* d_in, const int* in_sizes, int n_in,
                              void* d_out, int out_size, void* d_ws, size_t ws_size,
                              hipStream_t stream) {
  const float* t_feat = (const float*)d_in[0];
  const float* W1     = (const float*)d_in[1];
  const float* b1     = (const float*)d_in[2];
  const float* gamma  = (const float*)d_in[3];
  const float* beta   = (const float*)d_in[4];
  const float* W2     = (const float*)d_in[5];
  const float* b2     = (const float*)d_in[6];
  const float* cent   = (const float*)d_in[7];

  char* ws = (char*)d_ws;   // requires ws_size >= ~68 MiB (WS_END)
  unsigned short* tf  = (unsigned short*)(ws + WS_TF);
  unsigned short* w1h = (unsigned short*)(ws + WS_W1H);
  unsigned short* w1l = (unsigned short*)(ws + WS_W1L);
  unsigned short* w2h = (unsigned short*)(ws + WS_W2H);
  unsigned short* w2l = (unsigned short*)(ws + WS_W2L);
  float* cnorm = (float*)(ws + WS_CN);
  float* accum = (float*)(ws + WS_ACC);
  float* out = (float*)d_out;

  prep_tf_k<<<2048, 256, 0, stream>>>(t_feat, tf);
  prep_w1_k<<<8192, 256, 0, stream>>>(W1, w1h, w1l);
  prep_w2_k<<<8192, 256, 0, stream>>>(W2, w2h, w2l);
  prep_cn_k<<<64, 64, 0, stream>>>(cent, cnorm, accum);
  router_main<<<4096, 256, 0, stream>>>(tf, w1h, w1l, w2h, w2l,
                                        b1, gamma, beta, b2, cent, cnorm, accum);
  finalize_k<<<1, 64, 0, stream>>>(accum, out);
}

// Round 2
// 518.936 us; speedup vs baseline: 1.1622x; 1.1622x over previous
//
#include <hip/hip_runtime.h>
#include <math.h>

// ---------------- problem constants ----------------
#define TASKS 64
#define NB    4096
#define TDI   512     // token dim (K of GEMM1)
#define HDI   256     // hidden dim
#define VDI   484     // visual dim

// ---------------- ws layout (bytes) ----------------
// bf16 arrays pre-tiled in exact per-lane fragment chunk order; the main
// kernel reads fragments DIRECTLY from global (L2) into VGPRs - no LDS staging.
#define WS_TF   ((size_t)0)                       // [64rb][16ks][4kg][64m][8]
#define WS_W1H  (WS_TF  + (size_t)2097152 * 2)    // [64t][16ks][4kg][256n][8]
#define WS_W1L  (WS_W1H + (size_t)8388608 * 2)
#define WS_W2H  (WS_W1L + (size_t)8388608 * 2)    // [64t][2pass][8ks][4kg][256n][8]
#define WS_W2L  (WS_W2H + (size_t)8388608 * 2)
#define WS_CN   (WS_W2L + (size_t)8388608 * 2)    // 64 f32 centroid norms
#define WS_ACC  (WS_CN + 256)                     // 64 f32 distance accumulators

// ---------------- LDS layout (bytes): only H' + vectors + reductions ----------------
#define LDS_HP 0          // 32768: H' [32kg][64m][8] bf16
#define LDS_B1 32768
#define LDS_G  33792
#define LDS_BE 34816
#define LDS_B2 35840      // 512 f32 (zero-padded)
#define LDS_CE 37888      // 512 f32 (zero-padded)
#define LDS_R0 39936      // 256 f32
#define LDS_R1 40960      // 256 f32
#define LDS_MU 41984      // 64 f32
#define LDS_RS 42240      // 64 f32
#define SMEM_BYTES 42496

typedef __bf16 bf16x8 __attribute__((ext_vector_type(8)));
typedef float  f32x4  __attribute__((ext_vector_type(4)));

__device__ __forceinline__ unsigned short f2bf(float x) {   // RNE float->bf16
  unsigned u = __float_as_uint(x);
  u += 0x7fffu + ((u >> 16) & 1u);
  return (unsigned short)(u >> 16);
}
__device__ __forceinline__ float bf2f(unsigned short h) {
  return __uint_as_float(((unsigned)h) << 16);
}

#define MFMA16(a, b, c) __builtin_amdgcn_mfma_f32_16x16x32_bf16((a), (b), (c), 0, 0, 0)

// ================= merged prepass: fp32 -> tiled bf16 (hi/lo split), output-linear =================
extern "C" __global__ void prep_all(const float* __restrict__ t_feat,
                                    const float* __restrict__ W1,
                                    const float* __restrict__ W2,
                                    const float* __restrict__ cent,
                                    unsigned short* __restrict__ tf,
                                    unsigned short* __restrict__ w1h,
                                    unsigned short* __restrict__ w1l,
                                    unsigned short* __restrict__ w2h,
                                    unsigned short* __restrict__ w2l,
                                    float* __restrict__ cnorm,
                                    float* __restrict__ accum) {
  const int bid = blockIdx.x, tid = threadIdx.x;
  if (bid < 2048) {                       // t_feat -> tf tiles
    int gid = bid * 256 + tid;            // [0, 524288)
    int j0 = (gid & 1) * 4, m = (gid >> 1) & 63, kg = (gid >> 7) & 3,
        ks = (gid >> 9) & 15, rb = gid >> 13;
    int b = rb * 64 + m, k = ks * 32 + kg * 8 + j0;
    float4 v = *(const float4*)(t_feat + (size_t)b * TDI + k);
    ushort4 u; u.x = f2bf(v.x); u.y = f2bf(v.y); u.z = f2bf(v.z); u.w = f2bf(v.w);
    *(ushort4*)(tf + (size_t)gid * 4) = u;
  } else if (bid < 10240) {               // W1 -> w1h/w1l tiles
    int gid = (bid - 2048) * 256 + tid;   // [0, 2097152)
    int j0 = (gid & 1) * 4, n = (gid >> 1) & 255, kg = (gid >> 9) & 3,
        ks = (gid >> 11) & 15, t = gid >> 15;
    int d = ks * 32 + kg * 8 + j0;
    float4 v = *(const float4*)(W1 + ((size_t)t * HDI + n) * TDI + d);
    ushort4 uh, ul;
    uh.x = f2bf(v.x); ul.x = f2bf(v.x - bf2f(uh.x));
    uh.y = f2bf(v.y); ul.y = f2bf(v.y - bf2f(uh.y));
    uh.z = f2bf(v.z); ul.z = f2bf(v.z - bf2f(uh.z));
    uh.w = f2bf(v.w); ul.w = f2bf(v.w - bf2f(uh.w));
    *(ushort4*)(w1h + (size_t)gid * 4) = uh;
    *(ushort4*)(w1l + (size_t)gid * 4) = ul;
  } else if (bid < 18432) {               // W2 -> w2h/w2l tiles (zero-padded 484->512)
    int gid = (bid - 10240) * 256 + tid;  // [0, 2097152)
    int j0 = (gid & 1) * 4, n = (gid >> 1) & 255, kg = (gid >> 9) & 3,
        ks = (gid >> 11) & 7, pass = (gid >> 14) & 1, t = gid >> 15;
    int vv = pass * 256 + n, h = ks * 32 + kg * 8 + j0;
    float4 v; v.x = 0.f; v.y = 0.f; v.z = 0.f; v.w = 0.f;
    if (vv < VDI) v = *(const float4*)(W2 + ((size_t)t * VDI + vv) * HDI + h);
    ushort4 uh, ul;
    uh.x = f2bf(v.x); ul.x = f2bf(v.x - bf2f(uh.x));
    uh.y = f2bf(v.y); ul.y = f2bf(v.y - bf2f(uh.y));
    uh.z = f2bf(v.z); ul.z = f2bf(v.z - bf2f(uh.z));
    uh.w = f2bf(v.w); ul.w = f2bf(v.w - bf2f(uh.w));
    *(ushort4*)(w2h + (size_t)gid * 4) = uh;
    *(ushort4*)(w2l + (size_t)gid * 4) = ul;
  } else {                                // centroid norms + zero accumulators
    int t = bid - 18432;
    __shared__ float red[256];
    float s = 0.f;
    for (int v2 = tid; v2 < VDI; v2 += 256) { float c = cent[(size_t)t * VDI + v2]; s += c * c; }
    red[tid] = s;
    __syncthreads();
    if (tid < 64) {
      s = red[tid] + red[tid + 64] + red[tid + 128] + red[tid + 192];
      #pragma unroll
      for (int off = 32; off; off >>= 1) s += __shfl_xor(s, off);
      if (tid == 0) { cnorm[t] = sqrtf(s); accum[t] = 0.f; }
    }
  }
}

// ================= fused main kernel =================
#define LOADA1(D, KS) do { int c_ = aBase + (KS) * 256;                       \
  D[0] = tfv[c_]; D[1] = tfv[c_ + 16]; D[2] = tfv[c_ + 32]; D[3] = tfv[c_ + 48]; } while (0)

#define LOADB1(DH, DL, KS) do { int c_ = bBase + (KS) * 1024;                 \
  DH[0] = w1hv[c_]; DH[1] = w1hv[c_ + 16]; DH[2] = w1hv[c_ + 32]; DH[3] = w1hv[c_ + 48]; \
  DL[0] = w1lv[c_]; DL[1] = w1lv[c_ + 16]; DL[2] = w1lv[c_ + 32]; DL[3] = w1lv[c_ + 48]; } while (0)

#define LOADA2(D, KS) do { int o_ = ((((KS) * 4 + quad) * 64) + l15) * 16;    \
  D[0] = *(const bf16x8*)(smem + LDS_HP + o_);                                \
  D[1] = *(const bf16x8*)(smem + LDS_HP + o_ + 256);                          \
  D[2] = *(const bf16x8*)(smem + LDS_HP + o_ + 512);                          \
  D[3] = *(const bf16x8*)(smem + LDS_HP + o_ + 768); } while (0)

#define LOADB2(DH, DL, KS) do { int c_ = cBase + (KS) * 1024;                 \
  DH[0] = w2hv[c_]; DH[1] = w2hv[c_ + 16]; DH[2] = w2hv[c_ + 32]; DH[3] = w2hv[c_ + 48]; \
  DL[0] = w2lv[c_]; DL[1] = w2lv[c_ + 16]; DL[2] = w2lv[c_ + 32]; DL[3] = w2lv[c_ + 48]; } while (0)

#define STEP(ACC, A, BH, BL) do {                                             \
  _Pragma("unroll") for (int ct_ = 0; ct_ < 4; ++ct_) {                       \
    _Pragma("unroll") for (int rt_ = 0; rt_ < 4; ++rt_) {                     \
      ACC[rt_][ct_] = MFMA16(A[rt_], BH[ct_], ACC[rt_][ct_]);                 \
      ACC[rt_][ct_] = MFMA16(A[rt_], BL[ct_], ACC[rt_][ct_]);                 \
    } } } while (0)

extern "C" __global__ void __launch_bounds__(256, 2)
router_main(const bf16x8* __restrict__ tfv,
            const bf16x8* __restrict__ w1hv,
            const bf16x8* __restrict__ w1lv,
            const bf16x8* __restrict__ w2hv,
            const bf16x8* __restrict__ w2lv,
            const float* __restrict__ b1,
            const float* __restrict__ gamma,
            const float* __restrict__ beta,
            const float* __restrict__ b2,
            const float* __restrict__ cent,
            const float* __restrict__ cnorm,
            float* __restrict__ accum) {
  __shared__ __align__(16) char smem[SMEM_BYTES];

  const int tid = threadIdx.x;
  const int bx  = blockIdx.x;
  // XCD swizzle: each XCD (bx&7) handles one task at a time -> ~1MB weights stay L2-resident.
  const int t  = ((bx & 7) << 3) | (bx >> 9);
  const int rb = (bx >> 3) & 63;

  const int lane = tid & 63;
  const int w    = tid >> 6;
  const int quad = lane >> 4;
  const int l15  = lane & 15;

  // ---- preload per-task vectors into LDS (no barrier needed until phase 2) ----
  {
    ((float*)(smem + LDS_B1))[tid] = b1[t * HDI + tid];
    ((float*)(smem + LDS_G ))[tid] = gamma[t * HDI + tid];
    ((float*)(smem + LDS_BE))[tid] = beta[t * HDI + tid];
    float* b2s = (float*)(smem + LDS_B2);
    float* ces = (float*)(smem + LDS_CE);
    b2s[tid] = b2[(size_t)t * VDI + tid];
    ces[tid] = cent[(size_t)t * VDI + tid];
    int i1 = tid + 256;
    b2s[i1] = (i1 < VDI) ? b2[(size_t)t * VDI + i1] : 0.f;
    ces[i1] = (i1 < VDI) ? cent[(size_t)t * VDI + i1] : 0.f;
  }

  f32x4 zero4 = {0.f, 0.f, 0.f, 0.f};
  f32x4 acc[4][4];
  #pragma unroll
  for (int rt = 0; rt < 4; ++rt)
    #pragma unroll
    for (int ct = 0; ct < 4; ++ct) acc[rt][ct] = zero4;

  bf16x8 a0[4], a1[4], bh0[4], bh1[4], bl0[4], bl1[4];

  // ================= Phase 1: GEMM1, barrier-free, frags direct from L2 =================
  {
    const int aBase = rb * 4096 + quad * 64 + l15;
    const int bBase = t * 16384 + quad * 256 + w * 64 + l15;
    LOADA1(a0, 0); LOADB1(bh0, bl0, 0);
    #pragma unroll 1
    for (int ks = 0; ks < 16; ks += 2) {
      LOADA1(a1, ks + 1); LOADB1(bh1, bl1, ks + 1);
      STEP(acc, a0, bh0, bl0);
      int ksn = (ks + 2 < 16) ? ks + 2 : 15;   // clamped; last-iter result unused
      LOADA1(a0, ksn); LOADB1(bh0, bl0, ksn);
      STEP(acc, a1, bh1, bl1);
    }
  }

  // ================= Phase 2: +b1, LayerNorm, exact GELU -> H' (bf16) in LDS =================
  __syncthreads();   // vectors visible; all phase-1 consumers done
  {
    const float* b1s = (const float*)(smem + LDS_B1);
    float* red0 = (float*)(smem + LDS_R0);
    float* red1 = (float*)(smem + LDS_R1);
    #pragma unroll
    for (int rt = 0; rt < 4; ++rt)
      #pragma unroll
      for (int r = 0; r < 4; ++r) {
        float sv = 0.f, qv = 0.f;
        #pragma unroll
        for (int ct = 0; ct < 4; ++ct) {
          int col = w * 64 + ct * 16 + l15;
          float v = acc[rt][ct][r] + b1s[col];
          acc[rt][ct][r] = v;
          sv += v; qv += v * v;
        }
        sv += __shfl_xor(sv, 1); qv += __shfl_xor(qv, 1);
        sv += __shfl_xor(sv, 2); qv += __shfl_xor(qv, 2);
        sv += __shfl_xor(sv, 4); qv += __shfl_xor(qv, 4);
        sv += __shfl_xor(sv, 8); qv += __shfl_xor(qv, 8);
        if (l15 == 0) {
          int m = rt * 16 + quad * 4 + r;
          red0[w * 64 + m] = sv;
          red1[w * 64 + m] = qv;
        }
      }
    __syncthreads();
    if (tid < 64) {
      float s = red0[tid] + red0[64 + tid] + red0[128 + tid] + red0[192 + tid];
      float q = red1[tid] + red1[64 + tid] + red1[128 + tid] + red1[192 + tid];
      float mu = s * (1.f / HDI);
      float var = q * (1.f / HDI) - mu * mu;
      ((float*)(smem + LDS_MU))[tid] = mu;
      ((float*)(smem + LDS_RS))[tid] = rsqrtf(var + 1e-5f);
    }
    __syncthreads();
    const float* mus = (const float*)(smem + LDS_MU);
    const float* rss = (const float*)(smem + LDS_RS);
    const float* gs  = (const float*)(smem + LDS_G);
    const float* bes = (const float*)(smem + LDS_BE);
    #pragma unroll
    for (int rt = 0; rt < 4; ++rt)
      #pragma unroll
      for (int ct = 0; ct < 4; ++ct)
        #pragma unroll
        for (int r = 0; r < 4; ++r) {
          int col = w * 64 + ct * 16 + l15;
          int m   = rt * 16 + quad * 4 + r;
          float x = (acc[rt][ct][r] - mus[m]) * rss[m];
          x = x * gs[col] + bes[col];
          float g = 0.5f * x * (1.f + erff(x * 0.70710678118654752f));
          *(unsigned short*)(smem + LDS_HP + (size_t)((col >> 3) * 64 + m) * 16 + (col & 7) * 2) = f2bf(g);
        }
    __syncthreads();
  }

  // ================= Phase 3: GEMM2 (2 N-passes of 256), barrier-free K-loop =================
  float dotp[16], ssp[16];
  #pragma unroll
  for (int i = 0; i < 16; ++i) { dotp[i] = 0.f; ssp[i] = 0.f; }
  const float* b2s = (const float*)(smem + LDS_B2);
  const float* ces = (const float*)(smem + LDS_CE);

  #pragma unroll 1
  for (int pass = 0; pass < 2; ++pass) {
    const int cBase = (t * 2 + pass) * 8192 + quad * 256 + w * 64 + l15;
    f32x4 acc2[4][4];
    #pragma unroll
    for (int rt = 0; rt < 4; ++rt)
      #pragma unroll
      for (int ct = 0; ct < 4; ++ct) acc2[rt][ct] = zero4;

    LOADA2(a0, 0); LOADB2(bh0, bl0, 0);
    #pragma unroll 1
    for (int ks = 0; ks < 8; ks += 2) {
      LOADA2(a1, ks + 1); LOADB2(bh1, bl1, ks + 1);
      STEP(acc2, a0, bh0, bl0);
      int ksn = (ks + 2 < 8) ? ks + 2 : 7;     // clamped; last-iter result unused
      LOADA2(a0, ksn); LOADB2(bh0, bl0, ksn);
      STEP(acc2, a1, bh1, bl1);
    }

    // epilogue: accumulate v.c and |v|^2 per row (V never materialized)
    #pragma unroll
    for (int rt = 0; rt < 4; ++rt)
      #pragma unroll
      for (int ct = 0; ct < 4; ++ct)
        #pragma unroll
        for (int r = 0; r < 4; ++r) {
          int vcol = pass * 256 + w * 64 + ct * 16 + l15;
          if (vcol < VDI) {
            float val = acc2[rt][ct][r] + b2s[vcol];
            int i = rt * 4 + r;
            dotp[i] += val * ces[vcol];
            ssp[i]  += val * val;
          }
        }
  }

  // reduce per-row dot/ss across 16 col-lanes, then across waves via LDS
  #pragma unroll
  for (int i = 0; i < 16; ++i) {
    dotp[i] += __shfl_xor(dotp[i], 1); ssp[i] += __shfl_xor(ssp[i], 1);
    dotp[i] += __shfl_xor(dotp[i], 2); ssp[i] += __shfl_xor(ssp[i], 2);
    dotp[i] += __shfl_xor(dotp[i], 4); ssp[i] += __shfl_xor(ssp[i], 4);
    dotp[i] += __shfl_xor(dotp[i], 8); ssp[i] += __shfl_xor(ssp[i], 8);
  }
  {
    float* red0 = (float*)(smem + LDS_R0);
    float* red1 = (float*)(smem + LDS_R1);
    if (l15 == 0) {
      #pragma unroll
      for (int rt = 0; rt < 4; ++rt)
        #pragma unroll
        for (int r = 0; r < 4; ++r) {
          int m = rt * 16 + quad * 4 + r;
          red0[w * 64 + m] = dotp[rt * 4 + r];
          red1[w * 64 + m] = ssp[rt * 4 + r];
        }
    }
    __syncthreads();
    if (tid < 64) {
      float dot = red0[tid] + red0[64 + tid] + red0[128 + tid] + red0[192 + tid];
      float ss  = red1[tid] + red1[64 + tid] + red1[128 + tid] + red1[192 + tid];
      float cn  = fmaxf(cnorm[t], 1e-8f);
      float vn  = fmaxf(sqrtf(ss), 1e-8f);
      float part = 1.0f - dot / (vn * cn);
      part += __shfl_down(part, 32);
      part += __shfl_down(part, 16);
      part += __shfl_down(part, 8);
      part += __shfl_down(part, 4);
      part += __shfl_down(part, 2);
      part += __shfl_down(part, 1);
      if (tid == 0) atomicAdd(accum + t, part);
    }
  }
}

// ================= finalize: mean, argmin =================
extern "C" __global__ void finalize_k(const float* __restrict__ accum, float* __restrict__ out) {
  int t = threadIdx.x;                               // <<<1, 64>>>
  float d = accum[t] * (1.0f / (float)NB);
  out[t] = d;
  float bd = d; int bi = t;
  #pragma unroll
  for (int off = 32; off; off >>= 1) {
    float od = __shfl_xor(bd, off);
    int   oi = __shfl_xor(bi, off);
    if (od < bd || (od == bd && oi < bi)) { bd = od; bi = oi; }   // first-min tie-break
  }
  if (t == 0) out[64] = (float)bi;
}

extern "C" void kernel_launch(void* const* d_in, const int* in_sizes, int n_in,
                              void* d_out, int out_size, void* d_ws, size_t ws_size,
                              hipStream_t stream) {
  const float* t_feat = (const float*)d_in[0];
  const float* W1     = (const float*)d_in[1];
  const float* b1     = (const float*)d_in[2];
  const float* gamma  = (const float*)d_in[3];
  const float* beta   = (const float*)d_in[4];
  const float* W2     = (const float*)d_in[5];
  const float* b2     = (const float*)d_in[6];
  const float* cent   = (const float*)d_in[7];

  char* ws = (char*)d_ws;   // requires ws_size >= ~68 MiB
  unsigned short* tf  = (unsigned short*)(ws + WS_TF);
  unsigned short* w1h = (unsigned short*)(ws + WS_W1H);
  unsigned short* w1l = (unsigned short*)(ws + WS_W1L);
  unsigned short* w2h = (unsigned short*)(ws + WS_W2H);
  unsigned short* w2l = (unsigned short*)(ws + WS_W2L);
  float* cnorm = (float*)(ws + WS_CN);
  float* accum = (float*)(ws + WS_ACC);
  float* out = (float*)d_out;

  prep_all<<<18496, 256, 0, stream>>>(t_feat, W1, W2, cent, tf, w1h, w1l, w2h, w2l, cnorm, accum);
  router_main<<<4096, 256, 0, stream>>>((const bf16x8*)tf, (const bf16x8*)w1h, (const bf16x8*)w1l,
                                        (const bf16x8*)w2h, (const bf16x8*)w2l,
                                        b1, gamma, beta, b2, cent, cnorm, accum);
  finalize_k<<<1, 64, 0, stream>>>(accum, out);
}